// Round 1
// baseline (66.905 us; speedup 1.0000x reference)
//
#include <hip/hip_runtime.h>

#define DEV __device__ __forceinline__

// Truncated (level-3) signature state: s[0..3]=s1, s[4..19]=s2 (i*4+j),
// s[20..83]=s3 (i*16+j*4+k).

// s <- s (x) exp(dx)   (one Chen scan step; matches the reference update)
DEV void sig_step(float s[84], const float dx[4]) {
    float h[4], w[16], q[16];
#pragma unroll
    for (int j = 0; j < 4; ++j) h[j] = 0.5f * dx[j];
#pragma unroll
    for (int j = 0; j < 4; ++j)
#pragma unroll
        for (int k = 0; k < 4; ++k) {
            w[j * 4 + k] = h[j] * dx[k];              // dx_j dx_k / 2
            q[j * 4 + k] = w[j * 4 + k] * (1.0f / 3.0f); // dx_j dx_k / 6
        }
    // s3 += s2 (x) dx + s1 (x) (dx^2/2) + dx^3/6   (uses OLD s1,s2)
#pragma unroll
    for (int i = 0; i < 4; ++i)
#pragma unroll
        for (int j = 0; j < 4; ++j)
#pragma unroll
            for (int k = 0; k < 4; ++k) {
                float v = s[20 + i * 16 + j * 4 + k];
                v = fmaf(s[4 + i * 4 + j], dx[k], v);
                v = fmaf(s[i], w[j * 4 + k], v);
                v = fmaf(dx[i], q[j * 4 + k], v);
                s[20 + i * 16 + j * 4 + k] = v;
            }
    // s2 += s1 (x) dx + dx^2/2
#pragma unroll
    for (int i = 0; i < 4; ++i)
#pragma unroll
        for (int j = 0; j < 4; ++j) {
            float v = fmaf(s[i], dx[j], s[4 + i * 4 + j]);
            s[4 + i * 4 + j] = v + w[i * 4 + j];
        }
#pragma unroll
    for (int i = 0; i < 4; ++i) s[i] += dx[i];
}

// a <- a (x) b  (truncated tensor-algebra product, Chen's relation)
DEV void chen_mul(float a[84], const float b[84]) {
#pragma unroll
    for (int i = 0; i < 4; ++i)
#pragma unroll
        for (int j = 0; j < 4; ++j)
#pragma unroll
            for (int k = 0; k < 4; ++k) {
                float v = a[20 + i * 16 + j * 4 + k] + b[20 + i * 16 + j * 4 + k];
                v = fmaf(a[4 + i * 4 + j], b[k], v);
                v = fmaf(a[i], b[4 + j * 4 + k], v);
                a[20 + i * 16 + j * 4 + k] = v;
            }
#pragma unroll
    for (int i = 0; i < 4; ++i)
#pragma unroll
        for (int j = 0; j < 4; ++j) {
            float v = a[4 + i * 4 + j] + b[4 + i * 4 + j];
            a[4 + i * 4 + j] = fmaf(a[i], b[j], v);
        }
#pragma unroll
    for (int i = 0; i < 4; ++i) a[i] += b[i];
}

// Geometry: B=64, T=1024, E=64, D=4. 16 leaves of 64 frames per (b,e).
// ws layout: sig[b][c][84][64(e)]  then  bdx[b][c][4][64(e)]  (c=0 slot unused)

__global__ __launch_bounds__(64, 1) void leaf_kernel(const float* __restrict__ x,
                                                     float* __restrict__ sig,
                                                     float* __restrict__ bdx) {
    const int b = blockIdx.x >> 4;
    const int c = blockIdx.x & 15;
    const int e = threadIdx.x;
    const float4* xf = reinterpret_cast<const float4*>(x);
    const int base = b * 1024 * 64;
    const int t0 = c * 64;

    float4 prev = xf[base + t0 * 64 + e];
    if (c > 0) {
        float4 pm = xf[base + (t0 - 1) * 64 + e];
        const int bb = ((b * 16 + c) * 4) * 64 + e;
        bdx[bb + 0]   = prev.x - pm.x;
        bdx[bb + 64]  = prev.y - pm.y;
        bdx[bb + 128] = prev.z - pm.z;
        bdx[bb + 192] = prev.w - pm.w;
    }

    float s[84];
#pragma unroll
    for (int i = 0; i < 84; ++i) s[i] = 0.0f;

    float4 nxt = xf[base + (t0 + 1) * 64 + e];
    for (int i = 1; i < 64; ++i) {
        float4 cur = nxt;
        if (i < 63) nxt = xf[base + (t0 + i + 1) * 64 + e];  // 1-deep prefetch
        float dx[4] = {cur.x - prev.x, cur.y - prev.y, cur.z - prev.z, cur.w - prev.w};
        prev = cur;
        sig_step(s, dx);
    }

    const int sb = ((b * 16 + c) * 84) * 64 + e;
#pragma unroll
    for (int t = 0; t < 84; ++t) sig[sb + t * 64] = s[t];
}

__global__ __launch_bounds__(64, 1) void combine_kernel(const float* __restrict__ sig,
                                                        const float* __restrict__ bdx,
                                                        float* __restrict__ out) {
    const int pg = blockIdx.x % 15;
    const int b  = blockIdx.x / 15;
    const int e  = threadIdx.x;
    int lvl, p;
    if (pg == 0)     { lvl = 0; p = 0; }
    else if (pg < 3) { lvl = 1; p = pg - 1; }
    else if (pg < 7) { lvl = 2; p = pg - 3; }
    else             { lvl = 3; p = pg - 7; }
    const int G  = 16 >> lvl;
    const int k0 = p * G;

    float acc[84];
    {
        const int sb = ((b * 16 + k0) * 84) * 64 + e;
#pragma unroll
        for (int t = 0; t < 84; ++t) acc[t] = sig[sb + t * 64];
    }
    for (int k = 1; k < G; ++k) {
        const int kk = k0 + k;
        float dx[4];
        const int bb = ((b * 16 + kk) * 4) * 64 + e;
#pragma unroll
        for (int j = 0; j < 4; ++j) dx[j] = bdx[bb + j * 64];
        sig_step(acc, dx);                 // acc (x) exp(boundary dx)
        float bs[84];
        const int sb = ((b * 16 + kk) * 84) * 64 + e;
#pragma unroll
        for (int t = 0; t < 84; ++t) bs[t] = sig[sb + t * 64];
        chen_mul(acc, bs);                 // acc (x) leaf
    }

    const int ob = ((b * 64 + e) * 15 + pg) * 84;
#pragma unroll
    for (int t = 0; t < 84; ++t) out[ob + t] = acc[t];
}

// Fallback: direct sequential scan per (b, piece, e) — used only if ws too small.
__global__ __launch_bounds__(64, 1) void direct_kernel(const float* __restrict__ x,
                                                       float* __restrict__ out) {
    const int pg = blockIdx.x % 15;
    const int b  = blockIdx.x / 15;
    const int e  = threadIdx.x;
    int lvl, p;
    if (pg == 0)     { lvl = 0; p = 0; }
    else if (pg < 3) { lvl = 1; p = pg - 1; }
    else if (pg < 7) { lvl = 2; p = pg - 3; }
    else             { lvl = 3; p = pg - 7; }
    const int L  = 1024 >> lvl;
    const int t0 = p * L;
    const float4* xf = reinterpret_cast<const float4*>(x);
    const int base = b * 1024 * 64;

    float4 prev = xf[base + t0 * 64 + e];
    float s[84];
#pragma unroll
    for (int i = 0; i < 84; ++i) s[i] = 0.0f;
    for (int i = 1; i < L; ++i) {
        float4 cur = xf[base + (t0 + i) * 64 + e];
        float dx[4] = {cur.x - prev.x, cur.y - prev.y, cur.z - prev.z, cur.w - prev.w};
        prev = cur;
        sig_step(s, dx);
    }
    const int ob = ((b * 64 + e) * 15 + pg) * 84;
#pragma unroll
    for (int t = 0; t < 84; ++t) out[ob + t] = s[t];
}

extern "C" void kernel_launch(void* const* d_in, const int* in_sizes, int n_in,
                              void* d_out, int out_size, void* d_ws, size_t ws_size,
                              hipStream_t stream) {
    (void)in_sizes; (void)n_in; (void)out_size;
    const float* x = (const float*)d_in[0];
    float* out = (float*)d_out;

    const size_t sig_elems = (size_t)64 * 16 * 84 * 64;
    const size_t bdx_elems = (size_t)64 * 16 * 4 * 64;
    const size_t need = (sig_elems + bdx_elems) * sizeof(float);

    if (ws_size >= need) {
        float* sig = (float*)d_ws;
        float* bdx = sig + sig_elems;
        leaf_kernel<<<64 * 16, 64, 0, stream>>>(x, sig, bdx);
        combine_kernel<<<64 * 15, 64, 0, stream>>>(sig, bdx, out);
    } else {
        direct_kernel<<<64 * 15, 64, 0, stream>>>(x, out);
    }
}

// Round 2
// 43.103 us; speedup vs baseline: 1.5522x; 1.5522x over previous
//
#include <hip/hip_runtime.h>

#define DEV __device__ __forceinline__

// Truncated level-3 signature state: s1[4], s2[16] (i*4+j), s3[64] (i*16+j*4+k).

// s <- s (x) exp(dx). Optimized: 176 VALU ops.
// n3[ijk] = s3 + s2[ij]*dx[k] + (s1[i] + dx[i]/3) * (dx[j]*dx[k]/2)
// n2[ij]  = s2 + (s1[i] + dx[i]/2) * dx[j]
DEV void sig_step(float s1[4], float s2[16], float s3[64], const float dx[4]) {
    float w[16], u[4], g[4];
#pragma unroll
    for (int j = 0; j < 4; ++j) {
        float hj = 0.5f * dx[j];
        g[j] = s1[j] + hj;
        u[j] = fmaf(dx[j], (1.0f / 3.0f), s1[j]);
#pragma unroll
        for (int k = 0; k < 4; ++k) w[j * 4 + k] = hj * dx[k];
    }
#pragma unroll
    for (int i = 0; i < 4; ++i)
#pragma unroll
        for (int j = 0; j < 4; ++j)
#pragma unroll
            for (int k = 0; k < 4; ++k) {
                float v = s3[i * 16 + j * 4 + k];
                v = fmaf(s2[i * 4 + j], dx[k], v);
                v = fmaf(u[i], w[j * 4 + k], v);
                s3[i * 16 + j * 4 + k] = v;
            }
#pragma unroll
    for (int i = 0; i < 4; ++i)
#pragma unroll
        for (int j = 0; j < 4; ++j)
            s2[i * 4 + j] = fmaf(g[i], dx[j], s2[i * 4 + j]);
#pragma unroll
    for (int i = 0; i < 4; ++i) s1[i] += dx[i];
}

// s = exp(dx)  (first increment of a chunk; skips the zero-state step)
DEV void sig_init(float s1[4], float s2[16], float s3[64], const float dx[4]) {
#pragma unroll
    for (int i = 0; i < 4; ++i) s1[i] = dx[i];
#pragma unroll
    for (int j = 0; j < 4; ++j) {
        float hj = 0.5f * dx[j];
#pragma unroll
        for (int k = 0; k < 4; ++k) s2[j * 4 + k] = hj * dx[k];
    }
#pragma unroll
    for (int i = 0; i < 4; ++i) {
        float ti = dx[i] * (1.0f / 3.0f);
#pragma unroll
        for (int jk = 0; jk < 16; ++jk) s3[i * 16 + jk] = ti * s2[jk];
    }
}

// a <- a (x) b, with b read from a lane-based pointer with stride 64 floats/term.
DEV void chen_fold(float a1[4], float a2[16], float a3[64], const float* __restrict__ b) {
    float b1[4], b2[16];
#pragma unroll
    for (int k = 0; k < 4; ++k) b1[k] = b[k * 64];
#pragma unroll
    for (int t = 0; t < 16; ++t) b2[t] = b[(4 + t) * 64];
#pragma unroll
    for (int i = 0; i < 4; ++i)
#pragma unroll
        for (int j = 0; j < 4; ++j)
#pragma unroll
            for (int k = 0; k < 4; ++k) {
                float v = a3[i * 16 + j * 4 + k] + b[(20 + i * 16 + j * 4 + k) * 64];
                v = fmaf(a2[i * 4 + j], b1[k], v);
                v = fmaf(a1[i], b2[j * 4 + k], v);
                a3[i * 16 + j * 4 + k] = v;
            }
#pragma unroll
    for (int i = 0; i < 4; ++i)
#pragma unroll
        for (int j = 0; j < 4; ++j)
            a2[i * 4 + j] = fmaf(a1[i], b1[j], a2[i * 4 + j] + b2[i * 4 + j]);
#pragma unroll
    for (int i = 0; i < 4; ++i) a1[i] += b1[i];
}

DEV void store_sig(float* dst, const float s1[4], const float s2[16], const float s3[64]) {
#pragma unroll
    for (int t = 0; t < 4; ++t) dst[t * 64] = s1[t];
#pragma unroll
    for (int t = 0; t < 16; ++t) dst[(4 + t) * 64] = s2[t];
#pragma unroll
    for (int t = 0; t < 64; ++t) dst[(20 + t) * 64] = s3[t];
}

// Geometry: B=64, T=1024, E=64, D=4.
// piece_kernel: one block (256 thr = 4 waves) per (b, level-3 piece p).
// Each wave scans a 32-frame chunk (31 increments, exp-init), then the block
// tree-folds the 4 chunk sigs in LDS -> level-3 piece signature.
// Writes: l3sig[b][p][84][64e], bdxl3[b][p][4][64e] (p>0), out pieces 7..14.
__global__ __attribute__((amdgpu_flat_work_group_size(256, 256)))
__attribute__((amdgpu_waves_per_eu(2)))
void piece_kernel(const float* __restrict__ x, float* __restrict__ l3sig,
                  float* __restrict__ bdxl3, float* __restrict__ out) {
    __shared__ float sigbuf[2][84][64];
    __shared__ float bdxs[4][4][64];
    const int b = blockIdx.x >> 3;
    const int p = blockIdx.x & 7;
    const int w = threadIdx.x >> 6;
    const int e = threadIdx.x & 63;
    const float4* xf = reinterpret_cast<const float4*>(x);
    const long base = (long)b * 1024 * 64;
    const int c = p * 4 + w;       // global 32-frame chunk index (0..31)
    const int t0 = c * 32;

    float4 p0 = xf[base + (long)t0 * 64 + e];
    if (c > 0) {  // boundary increment: last frame of chunk c-1 -> first of c
        float4 pm = xf[base + (long)(t0 - 1) * 64 + e];
        float bx[4] = {p0.x - pm.x, p0.y - pm.y, p0.z - pm.z, p0.w - pm.w};
        if (w > 0) {
#pragma unroll
            for (int jj = 0; jj < 4; ++jj) bdxs[w][jj][e] = bx[jj];
        } else {  // piece boundary: export for treeB
            float* bb = &bdxl3[(((long)(b * 8 + p)) * 4) * 64 + e];
#pragma unroll
            for (int jj = 0; jj < 4; ++jj) bb[jj * 64] = bx[jj];
        }
    }

    float s1[4], s2[16], s3[64];
    float4 prev = p0;
    float4 cur = xf[base + (long)(t0 + 1) * 64 + e];
    {
        float dx[4] = {cur.x - prev.x, cur.y - prev.y, cur.z - prev.z, cur.w - prev.w};
        sig_init(s1, s2, s3, dx);
        prev = cur;
    }
    float4 nxt = xf[base + (long)(t0 + 2) * 64 + e];
    for (int i = 2; i < 32; ++i) {
        cur = nxt;
        if (i < 31) nxt = xf[base + (long)(t0 + i + 1) * 64 + e];
        float dx[4] = {cur.x - prev.x, cur.y - prev.y, cur.z - prev.z, cur.w - prev.w};
        prev = cur;
        sig_step(s1, s2, s3, dx);
    }

    // round 1: waves 1,3 publish; waves 0,2 fold (join via boundary dx)
    if (w == 1 || w == 3) store_sig(&sigbuf[w >> 1][0][e], s1, s2, s3);
    __syncthreads();
    if (w == 0 || w == 2) {
        float dxl[4] = {bdxs[w + 1][0][e], bdxs[w + 1][1][e], bdxs[w + 1][2][e], bdxs[w + 1][3][e]};
        sig_step(s1, s2, s3, dxl);
        chen_fold(s1, s2, s3, &sigbuf[w >> 1][0][e]);
    }
    __syncthreads();
    // round 2: wave 2 publishes; wave 0 folds -> full level-3 piece
    if (w == 2) store_sig(&sigbuf[0][0][e], s1, s2, s3);
    __syncthreads();
    if (w == 0) {
        float dxl[4] = {bdxs[2][0][e], bdxs[2][1][e], bdxs[2][2][e], bdxs[2][3][e]};
        sig_step(s1, s2, s3, dxl);
        chen_fold(s1, s2, s3, &sigbuf[0][0][e]);
        store_sig(&l3sig[(((long)(b * 8 + p)) * 84) * 64 + e], s1, s2, s3);
        // output piece index: level-3 pieces are pg 7..14
        float* ob = &out[(((long)(b * 64 + e)) * 15 + 7 + p) * 84];
#pragma unroll
        for (int t = 0; t < 4; ++t) ob[t] = s1[t];
#pragma unroll
        for (int t = 0; t < 16; ++t) ob[4 + t] = s2[t];
#pragma unroll
        for (int t = 0; t < 64; ++t) ob[20 + t] = s3[t];
    }
}

// treeB: outputs pg 0..6 by folding level-3 piece sigs.
// pg0 = pieces 0..7; pg1 = 0..3; pg2 = 4..7; pg3..6 = pairs (0,1)(2,3)(4,5)(6,7).
__global__ __attribute__((amdgpu_flat_work_group_size(64, 64)))
__attribute__((amdgpu_waves_per_eu(1)))
void treeB_kernel(const float* __restrict__ l3sig, const float* __restrict__ bdxl3,
                  float* __restrict__ out) {
    const int j = blockIdx.x % 7;
    const int b = blockIdx.x / 7;
    const int e = threadIdx.x;
    int s, n;
    if (j == 0)      { s = 0;           n = 8; }
    else if (j == 1) { s = 0;           n = 4; }
    else if (j == 2) { s = 4;           n = 4; }
    else             { s = (j - 3) * 2; n = 2; }

    float s1[4], s2[16], s3[64];
    {
        const float* src = &l3sig[(((long)(b * 8 + s)) * 84) * 64 + e];
#pragma unroll
        for (int t = 0; t < 4; ++t) s1[t] = src[t * 64];
#pragma unroll
        for (int t = 0; t < 16; ++t) s2[t] = src[(4 + t) * 64];
#pragma unroll
        for (int t = 0; t < 64; ++t) s3[t] = src[(20 + t) * 64];
    }
    for (int q = 1; q < n; ++q) {
        const float* bb = &bdxl3[(((long)(b * 8 + s + q)) * 4) * 64 + e];
        float dx[4] = {bb[0], bb[64], bb[128], bb[192]};
        sig_step(s1, s2, s3, dx);
        chen_fold(s1, s2, s3, &l3sig[(((long)(b * 8 + s + q)) * 84) * 64 + e]);
    }
    float* ob = &out[(((long)(b * 64 + e)) * 15 + j) * 84];
#pragma unroll
    for (int t = 0; t < 4; ++t) ob[t] = s1[t];
#pragma unroll
    for (int t = 0; t < 16; ++t) ob[4 + t] = s2[t];
#pragma unroll
    for (int t = 0; t < 64; ++t) ob[20 + t] = s3[t];
}

// Fallback: direct sequential scan per (b, piece) — only if ws is too small.
__global__ __attribute__((amdgpu_flat_work_group_size(64, 64)))
__attribute__((amdgpu_waves_per_eu(1)))
void direct_kernel(const float* __restrict__ x, float* __restrict__ out) {
    const int pg = blockIdx.x % 15;
    const int b = blockIdx.x / 15;
    const int e = threadIdx.x;
    int lvl, p;
    if (pg == 0)      { lvl = 0; p = 0; }
    else if (pg < 3)  { lvl = 1; p = pg - 1; }
    else if (pg < 7)  { lvl = 2; p = pg - 3; }
    else              { lvl = 3; p = pg - 7; }
    const int L = 1024 >> lvl;
    const int t0 = p * L;
    const float4* xf = reinterpret_cast<const float4*>(x);
    const long base = (long)b * 1024 * 64;

    float4 prev = xf[base + (long)t0 * 64 + e];
    float s1[4], s2[16], s3[64];
    {
        float4 cur = xf[base + (long)(t0 + 1) * 64 + e];
        float dx[4] = {cur.x - prev.x, cur.y - prev.y, cur.z - prev.z, cur.w - prev.w};
        sig_init(s1, s2, s3, dx);
        prev = cur;
    }
    for (int i = 2; i < L; ++i) {
        float4 cur = xf[base + (long)(t0 + i) * 64 + e];
        float dx[4] = {cur.x - prev.x, cur.y - prev.y, cur.z - prev.z, cur.w - prev.w};
        prev = cur;
        sig_step(s1, s2, s3, dx);
    }
    float* ob = &out[(((long)(b * 64 + e)) * 15 + pg) * 84];
#pragma unroll
    for (int t = 0; t < 4; ++t) ob[t] = s1[t];
#pragma unroll
    for (int t = 0; t < 16; ++t) ob[4 + t] = s2[t];
#pragma unroll
    for (int t = 0; t < 64; ++t) ob[20 + t] = s3[t];
}

extern "C" void kernel_launch(void* const* d_in, const int* in_sizes, int n_in,
                              void* d_out, int out_size, void* d_ws, size_t ws_size,
                              hipStream_t stream) {
    (void)in_sizes; (void)n_in; (void)out_size;
    const float* x = (const float*)d_in[0];
    float* out = (float*)d_out;

    const size_t l3_elems = (size_t)64 * 8 * 84 * 64;
    const size_t bdx_elems = (size_t)64 * 8 * 4 * 64;
    const size_t need = (l3_elems + bdx_elems) * sizeof(float);

    if (ws_size >= need) {
        float* l3sig = (float*)d_ws;
        float* bdxl3 = l3sig + l3_elems;
        piece_kernel<<<64 * 8, 256, 0, stream>>>(x, l3sig, bdxl3, out);
        treeB_kernel<<<64 * 7, 64, 0, stream>>>(l3sig, bdxl3, out);
    } else {
        direct_kernel<<<64 * 15, 64, 0, stream>>>(x, out);
    }
}

// Round 3
// 39.394 us; speedup vs baseline: 1.6983x; 1.0941x over previous
//
#include <hip/hip_runtime.h>

#define DEV __device__ __forceinline__

// Truncated level-3 signature state: s1[4], s2[16] (i*4+j), s3[64] (i*16+j*4+k).

// s <- s (x) exp(dx). 176 VALU ops.
// n3[ijk] = s3 + s2[ij]*dx[k] + (s1[i] + dx[i]/3) * (dx[j]*dx[k]/2)
// n2[ij]  = s2 + (s1[i] + dx[i]/2) * dx[j]
DEV void sig_step(float s1[4], float s2[16], float s3[64], const float dx[4]) {
    float w[16], u[4], g[4];
#pragma unroll
    for (int j = 0; j < 4; ++j) {
        float hj = 0.5f * dx[j];
        g[j] = s1[j] + hj;
        u[j] = fmaf(dx[j], (1.0f / 3.0f), s1[j]);
#pragma unroll
        for (int k = 0; k < 4; ++k) w[j * 4 + k] = hj * dx[k];
    }
#pragma unroll
    for (int i = 0; i < 4; ++i)
#pragma unroll
        for (int j = 0; j < 4; ++j)
#pragma unroll
            for (int k = 0; k < 4; ++k) {
                float v = s3[i * 16 + j * 4 + k];
                v = fmaf(s2[i * 4 + j], dx[k], v);
                v = fmaf(u[i], w[j * 4 + k], v);
                s3[i * 16 + j * 4 + k] = v;
            }
#pragma unroll
    for (int i = 0; i < 4; ++i)
#pragma unroll
        for (int j = 0; j < 4; ++j)
            s2[i * 4 + j] = fmaf(g[i], dx[j], s2[i * 4 + j]);
#pragma unroll
    for (int i = 0; i < 4; ++i) s1[i] += dx[i];
}

// s = exp(dx)  (first increment of a chunk)
DEV void sig_init(float s1[4], float s2[16], float s3[64], const float dx[4]) {
#pragma unroll
    for (int i = 0; i < 4; ++i) s1[i] = dx[i];
#pragma unroll
    for (int j = 0; j < 4; ++j) {
        float hj = 0.5f * dx[j];
#pragma unroll
        for (int k = 0; k < 4; ++k) s2[j * 4 + k] = hj * dx[k];
    }
#pragma unroll
    for (int i = 0; i < 4; ++i) {
        float ti = dx[i] * (1.0f / 3.0f);
#pragma unroll
        for (int jk = 0; jk < 16; ++jk) s3[i * 16 + jk] = ti * s2[jk];
    }
}

// a <- a (x) b, b read with stride 64 floats/term (works for LDS or global).
DEV void chen_fold(float a1[4], float a2[16], float a3[64], const float* __restrict__ b) {
    float b1[4], b2[16];
#pragma unroll
    for (int k = 0; k < 4; ++k) b1[k] = b[k * 64];
#pragma unroll
    for (int t = 0; t < 16; ++t) b2[t] = b[(4 + t) * 64];
#pragma unroll
    for (int i = 0; i < 4; ++i)
#pragma unroll
        for (int j = 0; j < 4; ++j)
#pragma unroll
            for (int k = 0; k < 4; ++k) {
                float v = a3[i * 16 + j * 4 + k] + b[(20 + i * 16 + j * 4 + k) * 64];
                v = fmaf(a2[i * 4 + j], b1[k], v);
                v = fmaf(a1[i], b2[j * 4 + k], v);
                a3[i * 16 + j * 4 + k] = v;
            }
#pragma unroll
    for (int i = 0; i < 4; ++i)
#pragma unroll
        for (int j = 0; j < 4; ++j)
            a2[i * 4 + j] = fmaf(a1[i], b1[j], a2[i * 4 + j] + b2[i * 4 + j]);
#pragma unroll
    for (int i = 0; i < 4; ++i) a1[i] += b1[i];
}

DEV void store_sig(float* dst, const float s1[4], const float s2[16], const float s3[64]) {
#pragma unroll
    for (int t = 0; t < 4; ++t) dst[t * 64] = s1[t];
#pragma unroll
    for (int t = 0; t < 16; ++t) dst[(4 + t) * 64] = s2[t];
#pragma unroll
    for (int t = 0; t < 64; ++t) dst[(20 + t) * 64] = s3[t];
}

DEV void load_sig(const float* src, float s1[4], float s2[16], float s3[64]) {
#pragma unroll
    for (int t = 0; t < 4; ++t) s1[t] = src[t * 64];
#pragma unroll
    for (int t = 0; t < 16; ++t) s2[t] = src[(4 + t) * 64];
#pragma unroll
    for (int t = 0; t < 64; ++t) s3[t] = src[(20 + t) * 64];
}

DEV void write_out(float* ob, const float s1[4], const float s2[16], const float s3[64]) {
#pragma unroll
    for (int t = 0; t < 4; ++t) ob[t] = s1[t];
#pragma unroll
    for (int t = 0; t < 16; ++t) ob[4 + t] = s2[t];
#pragma unroll
    for (int t = 0; t < 64; ++t) ob[20 + t] = s3[t];
}

// Geometry: B=64, T=1024, E=64, D=4.
// piece_kernel: block (256 thr = 4 waves) per (b, level-3 piece p). Wave w scans
// the 32-frame chunk c = 4p+w with a depth-4 rotating prefetch, then the block
// tree-folds 4 chunk sigs in LDS. Wave 0 writes l3sig/bdxl3 (ws) and out pg 7+p.
__global__ __attribute__((amdgpu_flat_work_group_size(256, 256)))
__attribute__((amdgpu_waves_per_eu(2)))
void piece_kernel(const float* __restrict__ x, float* __restrict__ l3sig,
                  float* __restrict__ bdxl3, float* __restrict__ out) {
    __shared__ float sigbuf[2][84][64];
    __shared__ float bdxs[4][4][64];
    const int b = blockIdx.x >> 3;
    const int p = blockIdx.x & 7;
    const int w = threadIdx.x >> 6;
    const int e = threadIdx.x & 63;
    const int c = p * 4 + w;
    // frame f of this chunk lives at xp[f * 64]
    const float4* xp = reinterpret_cast<const float4*>(x)
                     + (long)b * 65536 + (long)c * 32 * 64 + e;

    float4 prev = xp[0];
    if (c > 0) {  // boundary increment: last frame of chunk c-1 -> first of c
        float4 pm = xp[-64];
        float bx[4] = {prev.x - pm.x, prev.y - pm.y, prev.z - pm.z, prev.w - pm.w};
        if (w > 0) {
#pragma unroll
            for (int jj = 0; jj < 4; ++jj) bdxs[w][jj][e] = bx[jj];
        } else {  // level-3 piece boundary: export for treeB
            float* bb = &bdxl3[(((long)(b * 8 + p)) * 4) * 64 + e];
#pragma unroll
            for (int jj = 0; jj < 4; ++jj) bb[jj * 64] = bx[jj];
        }
    }

    // depth-4 rotating prefetch: buf[k] holds frame (k+1) initially
    float4 buf[4];
#pragma unroll
    for (int k = 0; k < 4; ++k) buf[k] = xp[(k + 1) * 64];

    float s1[4], s2[16], s3[64];
    {   // increment i=1 (slot 0)
        float4 cur = buf[0];
        float dx[4] = {cur.x - prev.x, cur.y - prev.y, cur.z - prev.z, cur.w - prev.w};
        sig_init(s1, s2, s3, dx);
        prev = cur;
        buf[0] = xp[5 * 64];
    }
    // increments i=2..29, 4-unrolled; load frame min(i+4,31) into the vacated slot
    for (int ii = 0; ii < 7; ++ii) {
#pragma unroll
        for (int j = 0; j < 4; ++j) {
            const int i = 2 + ii * 4 + j;
            const int slot = (j + 1) & 3;
            float4 cur = buf[slot];
            int li = i + 4; li = li > 31 ? 31 : li;
            buf[slot] = xp[li * 64];
            float dx[4] = {cur.x - prev.x, cur.y - prev.y, cur.z - prev.z, cur.w - prev.w};
            prev = cur;
            sig_step(s1, s2, s3, dx);
        }
    }
    // tail increments i=30 (slot 1), i=31 (slot 2); no more loads
#pragma unroll
    for (int j = 0; j < 2; ++j) {
        float4 cur = buf[1 + j];
        float dx[4] = {cur.x - prev.x, cur.y - prev.y, cur.z - prev.z, cur.w - prev.w};
        prev = cur;
        sig_step(s1, s2, s3, dx);
    }

    // round 1: waves 1,3 publish; waves 0,2 fold (join via boundary dx)
    if (w == 1 || w == 3) store_sig(&sigbuf[w >> 1][0][e], s1, s2, s3);
    __syncthreads();
    if (w == 0 || w == 2) {
        float dxl[4] = {bdxs[w + 1][0][e], bdxs[w + 1][1][e], bdxs[w + 1][2][e], bdxs[w + 1][3][e]};
        sig_step(s1, s2, s3, dxl);
        chen_fold(s1, s2, s3, &sigbuf[w >> 1][0][e]);
    }
    __syncthreads();
    // round 2: wave 2 publishes; wave 0 folds -> full level-3 piece
    if (w == 2) store_sig(&sigbuf[0][0][e], s1, s2, s3);
    __syncthreads();
    if (w == 0) {
        float dxl[4] = {bdxs[2][0][e], bdxs[2][1][e], bdxs[2][2][e], bdxs[2][3][e]};
        sig_step(s1, s2, s3, dxl);
        chen_fold(s1, s2, s3, &sigbuf[0][0][e]);
        store_sig(&l3sig[(((long)(b * 8 + p)) * 84) * 64 + e], s1, s2, s3);
        write_out(&out[(((long)(b * 64 + e)) * 15 + 7 + p) * 84], s1, s2, s3);
    }
}

// treeB: one block (4 waves) per b. Round 1 -> pg3..6 (pair folds), round 2 ->
// pg1,pg2, round 3 -> pg0. Every fold's result is a required output.
__global__ __attribute__((amdgpu_flat_work_group_size(256, 256)))
__attribute__((amdgpu_waves_per_eu(1)))
void treeB_kernel(const float* __restrict__ l3sig, const float* __restrict__ bdxl3,
                  float* __restrict__ out) {
    __shared__ float sigbuf[2][84][64];
    const int b = blockIdx.x;
    const int w = threadIdx.x >> 6;
    const int e = threadIdx.x & 63;

    float s1[4], s2[16], s3[64];
    // round 1: wave w folds pieces (2w, 2w+1) -> pg 3+w
    load_sig(&l3sig[(((long)(b * 8 + 2 * w)) * 84) * 64 + e], s1, s2, s3);
    {
        const float* bb = &bdxl3[(((long)(b * 8 + 2 * w + 1)) * 4) * 64 + e];
        float dx[4] = {bb[0], bb[64], bb[128], bb[192]};
        sig_step(s1, s2, s3, dx);
        chen_fold(s1, s2, s3, &l3sig[(((long)(b * 8 + 2 * w + 1)) * 84) * 64 + e]);
    }
    write_out(&out[(((long)(b * 64 + e)) * 15 + 3 + w) * 84], s1, s2, s3);

    if (w == 1 || w == 3) store_sig(&sigbuf[w >> 1][0][e], s1, s2, s3);
    __syncthreads();
    // round 2: wave 0 -> pg1 (pieces 0..3), wave 2 -> pg2 (pieces 4..7)
    if (w == 0 || w == 2) {
        const int jp = (w == 0) ? 2 : 6;  // first piece of the right half
        const float* bb = &bdxl3[(((long)(b * 8 + jp)) * 4) * 64 + e];
        float dx[4] = {bb[0], bb[64], bb[128], bb[192]};
        sig_step(s1, s2, s3, dx);
        chen_fold(s1, s2, s3, &sigbuf[w >> 1][0][e]);
        write_out(&out[(((long)(b * 64 + e)) * 15 + 1 + (w >> 1)) * 84], s1, s2, s3);
    }
    __syncthreads();
    // round 3: wave 2 publishes; wave 0 -> pg0 (pieces 0..7)
    if (w == 2) store_sig(&sigbuf[0][0][e], s1, s2, s3);
    __syncthreads();
    if (w == 0) {
        const float* bb = &bdxl3[(((long)(b * 8 + 4)) * 4) * 64 + e];
        float dx[4] = {bb[0], bb[64], bb[128], bb[192]};
        sig_step(s1, s2, s3, dx);
        chen_fold(s1, s2, s3, &sigbuf[0][0][e]);
        write_out(&out[(((long)(b * 64 + e)) * 15 + 0) * 84], s1, s2, s3);
    }
}

// Fallback: direct sequential scan per (b, piece) — only if ws is too small.
__global__ __attribute__((amdgpu_flat_work_group_size(64, 64)))
__attribute__((amdgpu_waves_per_eu(1)))
void direct_kernel(const float* __restrict__ x, float* __restrict__ out) {
    const int pg = blockIdx.x % 15;
    const int b = blockIdx.x / 15;
    const int e = threadIdx.x;
    int lvl, p;
    if (pg == 0)      { lvl = 0; p = 0; }
    else if (pg < 3)  { lvl = 1; p = pg - 1; }
    else if (pg < 7)  { lvl = 2; p = pg - 3; }
    else              { lvl = 3; p = pg - 7; }
    const int L = 1024 >> lvl;
    const int t0 = p * L;
    const float4* xf = reinterpret_cast<const float4*>(x);
    const long base = (long)b * 65536;

    float4 prev = xf[base + (long)t0 * 64 + e];
    float s1[4], s2[16], s3[64];
    {
        float4 cur = xf[base + (long)(t0 + 1) * 64 + e];
        float dx[4] = {cur.x - prev.x, cur.y - prev.y, cur.z - prev.z, cur.w - prev.w};
        sig_init(s1, s2, s3, dx);
        prev = cur;
    }
    for (int i = 2; i < L; ++i) {
        float4 cur = xf[base + (long)(t0 + i) * 64 + e];
        float dx[4] = {cur.x - prev.x, cur.y - prev.y, cur.z - prev.z, cur.w - prev.w};
        prev = cur;
        sig_step(s1, s2, s3, dx);
    }
    write_out(&out[(((long)(b * 64 + e)) * 15 + pg) * 84], s1, s2, s3);
}

extern "C" void kernel_launch(void* const* d_in, const int* in_sizes, int n_in,
                              void* d_out, int out_size, void* d_ws, size_t ws_size,
                              hipStream_t stream) {
    (void)in_sizes; (void)n_in; (void)out_size;
    const float* x = (const float*)d_in[0];
    float* out = (float*)d_out;

    const size_t l3_elems = (size_t)64 * 8 * 84 * 64;
    const size_t bdx_elems = (size_t)64 * 8 * 4 * 64;
    const size_t need = (l3_elems + bdx_elems) * sizeof(float);

    if (ws_size >= need) {
        float* l3sig = (float*)d_ws;
        float* bdxl3 = l3sig + l3_elems;
        piece_kernel<<<64 * 8, 256, 0, stream>>>(x, l3sig, bdxl3, out);
        treeB_kernel<<<64, 256, 0, stream>>>(l3sig, bdxl3, out);
    } else {
        direct_kernel<<<64 * 15, 64, 0, stream>>>(x, out);
    }
}